// Round 5
// baseline (341.585 us; speedup 1.0000x reference)
//
#include <hip/hip_runtime.h>

#define NPTS 16384
#define NNBR 32
#define CIN 16
#define COUT 16
#define NBASIS 16

// LDS f16 row stride 264 (528 B = 132 dw ≡ 4 mod 32): b128 reads alias 2-way (free).
#define WF_OS 264
#define ML_PS 264

// sqrt(10 * log2(e)) : exp(-10 d^2) == exp2(-(SCL*d)^2)
#define RSCL 3.7982825f

// Tile-ready flag value. Non-uniform bytes -> cannot collide with uniform-byte
// workspace poison patterns.
#define MAGIC 0x9E3779B9u

typedef _Float16 half8 __attribute__((ext_vector_type(8)));
typedef _Float16 half4 __attribute__((ext_vector_type(4)));
typedef unsigned short ushort8 __attribute__((ext_vector_type(8)));
typedef float floatx4 __attribute__((ext_vector_type(4)));

// ws layout (f16 units): [0, NPTS*16) xT16 [n][i] ; then 2048 u32 tile flags.
#define WS_XT 0
#define WS_FLAGS (NPTS * CIN)

static __device__ __forceinline__ unsigned short h2u(_Float16 h) {
    unsigned short u;
    __builtin_memcpy(&u, &h, 2);
    return u;
}

// Single fused kernel: 2048 blocks x 256 threads = exact co-residency capacity
// (8 blocks/CU x 4 waves = 32 waves/CU; LDS 14.75 KB x 8 = 118 KB < 160 KB;
// launch_bounds caps VGPR <= 64). Each block: transpose own 8 points -> ws,
// publish flag; consumers flag-check per-neighbor with a deadlock-free direct-
// load fallback. No cooperative grid sync (R1: grid.sync cost ~150 us).
__global__ __launch_bounds__(256, 8) void se3_fused(
        const float* __restrict__ input,     // (CIN, NPTS)
        const float* __restrict__ coords,    // (NPTS, 3)
        const float* __restrict__ W,         // (COUT, CIN, NBASIS)
        const float* __restrict__ centers,   // (NBASIS,)
        const float* __restrict__ mask,      // (NPTS, NNBR) f32
        const int* __restrict__ neighbors,   // (NPTS, NNBR)
        float* __restrict__ out,             // (COUT, NPTS)
        _Float16* __restrict__ ws) {
    __shared__ _Float16 Wf[COUT * WF_OS];        // 8448 B  [o][i*16+b]
    __shared__ _Float16 Mld[8 * ML_PS];          // 4224 B  [pq][i*16+b]
    __shared__ float    rs[8 * NNBR];            // 1024 B  (pre-scaled by RSCL)
    __shared__ unsigned short nb16[8 * NNBR];    //  512 B
    __shared__ _Float16 mv16[8 * NNBR];          //  512 B
    __shared__ unsigned int missA[8];            //   32 B  per-point miss bits

    unsigned int* F = (unsigned int*)&ws[WS_FLAGS];
    const _Float16* xT16 = &ws[WS_XT];

    const int tid = threadIdx.x;
    const int t = tid & 15;          // lane role (i in B / o in C)
    const int quad = (tid >> 4) & 3; // k-chunk select
    const int wv = tid >> 6;         // wave 0..3
    const int nbase = blockIdx.x * 8;

    // ---- Own-tile transpose FIRST (wave 0 only), flag published before wave0
    // issues any other loads, so consumers elsewhere unblock ASAP. Data goes
    // out as agent-scope atomic u64 stores -> coherent across XCDs by
    // construction (no reliance on L2 writeback subtleties).
    if (tid < 64) {
        if (tid < 32) {
            const int p = tid >> 2, c4 = tid & 3;
            const int nn = nbase + p;
            half4 v;
            #pragma unroll
            for (int j = 0; j < 4; ++j)
                v[j] = (_Float16)input[(c4 * 4 + j) * NPTS + nn];
            unsigned long long uv;
            __builtin_memcpy(&uv, &v, 8);
            __hip_atomic_store((unsigned long long*)&ws[WS_XT + nn * CIN + c4 * 4],
                               uv, __ATOMIC_RELAXED, __HIP_MEMORY_SCOPE_AGENT);
        }
        __threadfence();   // wave0: drain stores, order before flag release
        if (tid == 0)
            __hip_atomic_store(&F[blockIdx.x], MAGIC, __ATOMIC_RELEASE,
                               __HIP_MEMORY_SCOPE_AGENT);
    }

    // ---- Phase A loads (HBM-cold, longest latency): one (pt,k) per thread.
    const int pt = tid >> 5;
    const int k = tid & 31;
    const int n = nbase + pt;
    const int nbr = neighbors[n * NNBR + k] & (NPTS - 1);
    // Flag of MY neighbor's tile: each thread checks one; the wave's 64 checks
    // exactly cover the 64 neighbors its phase-B consumes (producer wave ==
    // consumer wave). Issued early -> latency hides under coords gathers.
    unsigned int fl = __hip_atomic_load(&F[nbr >> 3], __ATOMIC_RELAXED,
                                        __HIP_MEMORY_SCOPE_AGENT);
    const float m = mask[n * NNBR + k];
    const float nx = coords[n * 3 + 0], ny = coords[n * 3 + 1],
                nz = coords[n * 3 + 2];
    const float bx = coords[nbr * 3 + 0], by = coords[nbr * 3 + 1],
                bz = coords[nbr * 3 + 2];

    // ---- Stage Wf from global (L2-broadcast 16 KB): thread (o,i) reads 16
    // contiguous f32 (4x float4), writes 32 contiguous bytes f16 (2x b128).
    {
        const int o = tid >> 4, ci = tid & 15;
        const float4 w0 = *(const float4*)&W[o * 256 + ci * 16 + 0];
        const float4 w1 = *(const float4*)&W[o * 256 + ci * 16 + 4];
        const float4 w2 = *(const float4*)&W[o * 256 + ci * 16 + 8];
        const float4 w3 = *(const float4*)&W[o * 256 + ci * 16 + 12];
        half8 lo, hi;
        lo[0] = (_Float16)w0.x; lo[1] = (_Float16)w0.y;
        lo[2] = (_Float16)w0.z; lo[3] = (_Float16)w0.w;
        lo[4] = (_Float16)w1.x; lo[5] = (_Float16)w1.y;
        lo[6] = (_Float16)w1.z; lo[7] = (_Float16)w1.w;
        hi[0] = (_Float16)w2.x; hi[1] = (_Float16)w2.y;
        hi[2] = (_Float16)w2.z; hi[3] = (_Float16)w2.w;
        hi[4] = (_Float16)w3.x; hi[5] = (_Float16)w3.y;
        hi[6] = (_Float16)w3.z; hi[7] = (_Float16)w3.w;
        *(half8*)&Wf[o * WF_OS + ci * 16]     = lo;
        *(half8*)&Wf[o * WF_OS + ci * 16 + 8] = hi;
    }

    if (tid < 8) missA[tid] = 0;
    __syncthreads();   // missA init visible before any atomicOr below

    // ---- Phase A compute + LDS publish.
    {
        const float dx = bx - nx, dy = by - ny, dz = bz - nz;
        rs[pt * NNBR + k] =
            sqrtf(dx * dx + dy * dy + dz * dz + 1e-12f) * RSCL;
        nb16[pt * NNBR + k] = (unsigned short)nbr;
        mv16[pt * NNBR + k] = (_Float16)m;
    }
    // Spin briefly if my neighbor's tile isn't published yet; on timeout mark
    // it for the direct-load fallback (deadlock-free under any residency).
    if (fl != MAGIC) {
        int it = 0;
        while ((fl = __hip_atomic_load(&F[nbr >> 3], __ATOMIC_RELAXED,
                                       __HIP_MEMORY_SCOPE_AGENT)) != MAGIC) {
            if (++it >= 300) break;
            __builtin_amdgcn_s_sleep(1);
        }
        if (fl != MAGIC) atomicOr(&missA[pt], 1u << k);
    }
    __threadfence();   // acquire side of the flag handshake
    __syncthreads();

    // ---- Phase B: wave wv -> points 2wv, 2wv+1; one mfma_16x16x32_f16 each.
    // A[m=i=t][k=8q+j] = x[nbr][t]*mask ; B[k][n=b=t] = exp2(-(rscl-c_t)^2)
    const float cs = centers[t] * RSCL;
    const int kb0 = (wv * 2 + 0) * NNBR + 8 * quad;  // group-broadcast LDS
    const int kb1 = (wv * 2 + 1) * NNBR + 8 * quad;
    const ushort8 nbv0 = *(const ushort8*)&nb16[kb0];
    const ushort8 nbv1 = *(const ushort8*)&nb16[kb1];
    const half8 mvv0 = *(const half8*)&mv16[kb0];
    const half8 mvv1 = *(const half8*)&mv16[kb1];
    const float4 r00 = *(const float4*)&rs[kb0];
    const float4 r01 = *(const float4*)&rs[kb0 + 4];
    const float4 r10 = *(const float4*)&rs[kb1];
    const float4 r11 = *(const float4*)&rs[kb1 + 4];
    const unsigned int mm0 = (missA[wv * 2 + 0] >> (8 * quad)) & 0xffu;
    const unsigned int mm1 = (missA[wv * 2 + 1] >> (8 * quad)) & 0xffu;

    // All 16 x-gathers issued before exp work (agent-scope loads: coherent
    // with producer atomic stores; 32 B/16-lane-group).
    ushort8 u0, u1;
    #pragma unroll
    for (int j = 0; j < 8; ++j)
        u0[j] = __hip_atomic_load(
            (const unsigned short*)&xT16[(int)nbv0[j] * CIN + t],
            __ATOMIC_RELAXED, __HIP_MEMORY_SCOPE_AGENT);
    #pragma unroll
    for (int j = 0; j < 8; ++j)
        u1[j] = __hip_atomic_load(
            (const unsigned short*)&xT16[(int)nbv1[j] * CIN + t],
            __ATOMIC_RELAXED, __HIP_MEMORY_SCOPE_AGENT);
    if (mm0 | mm1) {   // rare: producer not seen -> read input directly
        #pragma unroll
        for (int j = 0; j < 8; ++j) {
            if (mm0 & (1u << j))
                u0[j] = h2u((_Float16)input[t * NPTS + (int)nbv0[j]]);
            if (mm1 & (1u << j))
                u1[j] = h2u((_Float16)input[t * NPTS + (int)nbv1[j]]);
        }
    }
    const half8 xh0 = *(const half8*)&u0;
    const half8 xh1 = *(const half8*)&u1;

    const float rj0[8] = {r00.x, r00.y, r00.z, r00.w, r01.x, r01.y, r01.z, r01.w};
    const float rj1[8] = {r10.x, r10.y, r10.z, r10.w, r11.x, r11.y, r11.z, r11.w};

    {   // q = 0
        half8 af, bf;
        #pragma unroll
        for (int j = 0; j < 8; ++j) {
            const float d = rj0[j] - cs;
            bf[j] = (_Float16)__builtin_amdgcn_exp2f(-(d * d));
        }
        af = xh0 * mvv0;
        floatx4 c = {0.0f, 0.0f, 0.0f, 0.0f};
        c = __builtin_amdgcn_mfma_f32_16x16x32_f16(af, bf, c, 0, 0, 0);
        // D[row=i=4quad+v][col=b=t] -> Mld[pq][(4quad+v)*16 + t]
        #pragma unroll
        for (int v = 0; v < 4; ++v)
            Mld[(wv * 2 + 0) * ML_PS + (4 * quad + v) * 16 + t] = (_Float16)c[v];
    }
    {   // q = 1
        half8 af, bf;
        #pragma unroll
        for (int j = 0; j < 8; ++j) {
            const float d = rj1[j] - cs;
            bf[j] = (_Float16)__builtin_amdgcn_exp2f(-(d * d));
        }
        af = xh1 * mvv1;
        floatx4 c = {0.0f, 0.0f, 0.0f, 0.0f};
        c = __builtin_amdgcn_mfma_f32_16x16x32_f16(af, bf, c, 0, 0, 0);
        #pragma unroll
        for (int v = 0; v < 4; ++v)
            Mld[(wv * 2 + 1) * ML_PS + (4 * quad + v) * 16 + t] = (_Float16)c[v];
    }
    __syncthreads();

    // ---- Phase C (every wave, redundant): Out = W(16x256) * Mflat(256x8).
    // Composite k-index bi = i*16+b, consistent on both operands.
    floatx4 acc = {0.0f, 0.0f, 0.0f, 0.0f};
    #pragma unroll
    for (int cch = 0; cch < 8; ++cch) {
        const int bi = cch * 32 + 8 * quad;
        const half8 a = *(const half8*)&Wf[t * WF_OS + bi];
        half8 b = {};
        if (t < 8) b = *(const half8*)&Mld[t * ML_PS + bi];
        acc = __builtin_amdgcn_mfma_f32_16x16x32_f16(a, b, acc, 0, 0, 0);
    }
    // D[row=o=4quad+v][col=pt=t]; wave wv stores cols 2wv, 2wv+1.
    if (t < 8 && wv == (t >> 1)) {
        #pragma unroll
        for (int v = 0; v < 4; ++v)
            out[(4 * quad + v) * NPTS + nbase + t] = acc[v];
    }
}

extern "C" void kernel_launch(void* const* d_in, const int* in_sizes, int n_in,
                              void* d_out, int out_size, void* d_ws, size_t ws_size,
                              hipStream_t stream) {
    const float* input   = (const float*)d_in[0];
    const float* coords  = (const float*)d_in[1];
    const float* W       = (const float*)d_in[2];
    const float* centers = (const float*)d_in[3];
    const float* mask    = (const float*)d_in[4];
    const int*   nbr     = (const int*)d_in[5];
    float* out = (float*)d_out;
    _Float16* ws = (_Float16*)d_ws;   // ~520 KB of the 256 MB workspace

    se3_fused<<<NPTS / 8, 256, 0, stream>>>(input, coords, W, centers, mask,
                                            nbr, out, ws);
}

// Round 6
// 73.012 us; speedup vs baseline: 4.6785x; 4.6785x over previous
//
#include <hip/hip_runtime.h>

#define NPTS 16384
#define NNBR 32
#define CIN 16
#define COUT 16
#define NBASIS 16

// LDS f16 row stride 264 (528 B = 132 dw ≡ 4 mod 32): b128 reads alias 2-way (free).
#define WF_OS 264
#define ML_PS 264

// sqrt(10 * log2(e)) : exp(-10 d^2) == exp2(-(SCL*d)^2)
#define RSCL 3.7982825f

typedef _Float16 half8 __attribute__((ext_vector_type(8)));
typedef _Float16 half4 __attribute__((ext_vector_type(4)));
typedef unsigned short ushort8 __attribute__((ext_vector_type(8)));
typedef float floatx4 __attribute__((ext_vector_type(4)));

// ws layout (f16 units): [0, NPTS*16) xT16 [n][i] ; then Wf16 [o][b*16+i]
#define WS_XT 0
#define WS_WF (NPTS * CIN)

// Prep: 256 blocks x 256 threads. Thread = (point-in-block p4 = tid>>2,
// channel-quad c4 = tid&3): reads input[c4*4+j][n] (coalesced along n within
// each lane-group), writes one contiguous 8 B f16x4. Block 0 packs W.
__global__ __launch_bounds__(256) void prep_kernel(
        const float* __restrict__ input, const float* __restrict__ W,
        _Float16* __restrict__ ws) {
    const int p4 = threadIdx.x >> 2;          // 0..63 point within block
    const int c4 = threadIdx.x & 3;           // channel quad
    const int n = blockIdx.x * 64 + p4;
    half4 v;
    #pragma unroll
    for (int j = 0; j < 4; ++j)
        v[j] = (_Float16)input[(c4 * 4 + j) * NPTS + n];
    *(half4*)&ws[WS_XT + n * CIN + c4 * 4] = v;
    if (blockIdx.x == 0) {   // W -> [o][b*16+i] f16
        const int o = threadIdx.x >> 4, b = threadIdx.x & 15;
        _Float16 w[16];
        #pragma unroll
        for (int i = 0; i < CIN; ++i) w[i] = (_Float16)W[o * 256 + i * 16 + b];
        *(half8*)&ws[WS_WF + o * 256 + b * 16]     = *(half8*)&w[0];
        *(half8*)&ws[WS_WF + o * 256 + b * 16 + 8] = *(half8*)&w[8];
    }
}

// Conv: 2048 blocks x 256 = 8 points/block. 8 blocks/CU x 4 waves = 32
// waves/CU (max TLP). LDS 14.7 KB.
//
// SINGLE-BARRIER structure: phases A and B are entirely intra-wave
// (rs/nb16/mv16 produced and consumed by the same wave; pt = tid>>5 covers
// exactly pq = 2wv..2wv+1). The only cross-wave edges are {Wf, Mld} -> phase
// C, so one __syncthreads() before phase C suffices. Waves pipeline through
// the latency-heavy gather+exp region independently instead of rendezvousing
// before it (the old post-A barrier exposed every wave's L3 gather latency).
__global__ __launch_bounds__(256, 8) void se3_conv_kernel(
        const _Float16* __restrict__ ws,
        const float* __restrict__ coords,    // (NPTS, 3)
        const float* __restrict__ centers,   // (NBASIS,)
        const float* __restrict__ mask,      // (NPTS, NNBR) f32
        const int* __restrict__ neighbors,   // (NPTS, NNBR)
        float* __restrict__ out) {           // (COUT, NPTS)
    __shared__ _Float16 Wf[COUT * WF_OS];        // 8448 B
    __shared__ _Float16 Mld[8 * ML_PS];          // 4224 B
    __shared__ float    rs[8 * NNBR];            // 1024 B  (pre-scaled by RSCL)
    __shared__ unsigned short nb16[8 * NNBR];    //  512 B
    __shared__ _Float16 mv16[8 * NNBR];          //  512 B

    const _Float16* xT16 = &ws[WS_XT];

    const int tid = threadIdx.x;
    const int t = tid & 15;          // lane role (i in B / o in C)
    const int quad = (tid >> 4) & 3; // k-chunk select
    const int wv = tid >> 6;         // wave 0..3
    const int nbase = blockIdx.x * 8;

    // ---- Phase A loads FIRST (HBM-cold, longest latency): one (pt,k) pair
    // per thread. pt = tid>>5, k = tid&31.
    const int pt = tid >> 5;
    const int k = tid & 31;
    const int n = nbase + pt;
    const int nbr = neighbors[n * NNBR + k] & (NPTS - 1);
    const float m = mask[n * NNBR + k];
    const float nx = coords[n * 3 + 0], ny = coords[n * 3 + 1],
                nz = coords[n * 3 + 2];
    const float bx = coords[nbr * 3 + 0], by = coords[nbr * 3 + 1],
                bz = coords[nbr * 3 + 2];

    // ---- Stage Wf while phase-A loads are in flight (consumed only after
    // the single barrier, in phase C).
    {
        const int o = tid >> 4, ch = tid & 15;
        const half8 w0 = *(const half8*)&ws[WS_WF + o * 256 + ch * 16];
        const half8 w1 = *(const half8*)&ws[WS_WF + o * 256 + ch * 16 + 8];
        *(half8*)&Wf[o * WF_OS + ch * 16]     = w0;
        *(half8*)&Wf[o * WF_OS + ch * 16 + 8] = w1;
    }

    // ---- Phase A compute + intra-wave LDS publish (lgkmcnt orders the
    // same-wave ds_write -> ds_read; no block barrier needed).
    {
        const float dx = bx - nx, dy = by - ny, dz = bz - nz;
        rs[pt * NNBR + k] =
            sqrtf(dx * dx + dy * dy + dz * dz + 1e-12f) * RSCL;
        nb16[pt * NNBR + k] = (unsigned short)nbr;
        mv16[pt * NNBR + k] = (_Float16)m;
    }

    // ---- Phase B (still pre-barrier): wave wv -> points 2wv, 2wv+1; one
    // mfma_16x16x32_f16 each.
    // A[m=i=t][k=8q+j] = x[nbr][t]*mask ; B[k][n=b=t] = exp2(-(rscl-c_t)^2)
    const float cs = centers[t] * RSCL;
    const int kb0 = (wv * 2 + 0) * NNBR + 8 * quad;  // group-broadcast LDS
    const int kb1 = (wv * 2 + 1) * NNBR + 8 * quad;
    const ushort8 nbv0 = *(const ushort8*)&nb16[kb0];
    const ushort8 nbv1 = *(const ushort8*)&nb16[kb1];
    const half8 mvv0 = *(const half8*)&mv16[kb0];
    const half8 mvv1 = *(const half8*)&mv16[kb1];
    const float4 r00 = *(const float4*)&rs[kb0];
    const float4 r01 = *(const float4*)&rs[kb0 + 4];
    const float4 r10 = *(const float4*)&rs[kb1];
    const float4 r11 = *(const float4*)&rs[kb1 + 4];

    // All 16 x-gathers issued before exp work; their L2/L3 latency now
    // overlaps other waves' phase A (no barrier in between anymore).
    half8 xh0, xh1;
    #pragma unroll
    for (int j = 0; j < 8; ++j) xh0[j] = xT16[(int)nbv0[j] * CIN + t];
    #pragma unroll
    for (int j = 0; j < 8; ++j) xh1[j] = xT16[(int)nbv1[j] * CIN + t];

    const float rj0[8] = {r00.x, r00.y, r00.z, r00.w, r01.x, r01.y, r01.z, r01.w};
    const float rj1[8] = {r10.x, r10.y, r10.z, r10.w, r11.x, r11.y, r11.z, r11.w};

    {   // q = 0
        half8 af, bf;
        #pragma unroll
        for (int j = 0; j < 8; ++j) {
            const float d = rj0[j] - cs;
            // v_exp_f32 is exp2 natively; negate folds into the src modifier.
            bf[j] = (_Float16)__builtin_amdgcn_exp2f(-(d * d));
        }
        af = xh0 * mvv0;                           // v_pk_mul_f16, no cvt chain
        floatx4 c = {0.0f, 0.0f, 0.0f, 0.0f};
        c = __builtin_amdgcn_mfma_f32_16x16x32_f16(af, bf, c, 0, 0, 0);
        _Float16 h[4];
        #pragma unroll
        for (int v = 0; v < 4; ++v) h[v] = (_Float16)c[v];
        // D[row=i=4quad+v][col=b=t] -> Mld[pq][t*16 + 4quad + v] (one b64)
        *(uint2*)&Mld[(wv * 2 + 0) * ML_PS + t * 16 + 4 * quad] = *(uint2*)h;
    }
    {   // q = 1
        half8 af, bf;
        #pragma unroll
        for (int j = 0; j < 8; ++j) {
            const float d = rj1[j] - cs;
            bf[j] = (_Float16)__builtin_amdgcn_exp2f(-(d * d));
        }
        af = xh1 * mvv1;
        floatx4 c = {0.0f, 0.0f, 0.0f, 0.0f};
        c = __builtin_amdgcn_mfma_f32_16x16x32_f16(af, bf, c, 0, 0, 0);
        _Float16 h[4];
        #pragma unroll
        for (int v = 0; v < 4; ++v) h[v] = (_Float16)c[v];
        *(uint2*)&Mld[(wv * 2 + 1) * ML_PS + t * 16 + 4 * quad] = *(uint2*)h;
    }

    __syncthreads();   // the ONLY barrier: {Wf, Mld} -> phase C

    // ---- Phase C (every wave, redundant): Out = W(16x256) * Mflat(256x8).
    // A[m=o=t][bi-chunk]; B[bi-chunk][n=pt=t] valid for t<8 (cols 8-15 zero).
    floatx4 acc = {0.0f, 0.0f, 0.0f, 0.0f};
    #pragma unroll
    for (int cch = 0; cch < 8; ++cch) {
        const int bi = cch * 32 + 8 * quad;
        const half8 a = *(const half8*)&Wf[t * WF_OS + bi];
        half8 b = {};
        if (t < 8) b = *(const half8*)&Mld[t * ML_PS + bi];
        acc = __builtin_amdgcn_mfma_f32_16x16x32_f16(a, b, acc, 0, 0, 0);
    }
    // D[row=o=4quad+v][col=pt=t]; wave wv stores cols 2wv, 2wv+1.
    if (t < 8 && wv == (t >> 1)) {
        #pragma unroll
        for (int v = 0; v < 4; ++v)
            out[(4 * quad + v) * NPTS + nbase + t] = acc[v];
    }
}

extern "C" void kernel_launch(void* const* d_in, const int* in_sizes, int n_in,
                              void* d_out, int out_size, void* d_ws, size_t ws_size,
                              hipStream_t stream) {
    const float* input   = (const float*)d_in[0];
    const float* coords  = (const float*)d_in[1];
    const float* W       = (const float*)d_in[2];
    const float* centers = (const float*)d_in[3];
    const float* mask    = (const float*)d_in[4];
    const int*   nbr     = (const int*)d_in[5];
    float* out = (float*)d_out;
    _Float16* ws = (_Float16*)d_ws;   // ~520 KB of the 256 MB workspace

    prep_kernel<<<NPTS / 64, 256, 0, stream>>>(input, W, ws);
    se3_conv_kernel<<<NPTS / 8, 256, 0, stream>>>(ws, coords, centers, mask,
                                                  nbr, out);
}